// Round 1
// baseline (1035.000 us; speedup 1.0000x reference)
//
#include <hip/hip_runtime.h>

// Attention_Layer: scores=d@e^T -> softmax -> value=attn@e -> tanh([value,d]@W+b)
// B=8 TE=4096 TD=1024 H=256 NH=256. f32 in/out.
// Strategy: flash-attention with bf16 MFMA; QK^T uses hi/lo bf16 split (3 MFMA)
// for near-f32 score precision; PV in plain bf16; dense epilogue f32 vector.

#define B_ 8
#define TE_ 4096
#define TD_ 1024
#define H_ 256

typedef __attribute__((ext_vector_type(8))) short s16x8;
typedef __attribute__((ext_vector_type(4))) float fx4;
typedef __attribute__((ext_vector_type(4))) unsigned short u16x4;

#define MFMA(a, b, c) __builtin_amdgcn_mfma_f32_16x16x32_bf16(a, b, c, 0, 0, 0)

__device__ __forceinline__ unsigned short f2bf(float x) {
  unsigned u = __float_as_uint(x);
  unsigned r = (u + 0x7fffu + ((u >> 16) & 1u)) >> 16;  // RNE
  return (unsigned short)r;
}
__device__ __forceinline__ float bf2f(unsigned short s) {
  return __uint_as_float(((unsigned)s) << 16);
}

// ---------------- prep_e: e(f32) -> e_hi, e_lo (row-major bf16) + eT_hi [B,H,TE]
__global__ __launch_bounds__(256) void prep_e(const float* __restrict__ e,
                                              unsigned short* __restrict__ ehi,
                                              unsigned short* __restrict__ elo,
                                              unsigned short* __restrict__ eT) {
  const int bid = blockIdx.x;          // 8 * 64 * 4 = 2048 blocks
  const int b = bid >> 8;
  const int s0 = ((bid >> 2) & 63) * 64;
  const int h0 = (bid & 3) * 64;
  const int tid = threadIdx.x;
  __shared__ unsigned short lt[64][65];  // odd pad: transposed-gather ~conflict-free

#pragma unroll
  for (int i = 0; i < 4; ++i) {
    const int row = (tid >> 4) + 16 * i;     // 0..63 (s-local)
    const int col = (tid & 15) * 4;          // 0..60 (h-local)
    const size_t go = (((size_t)b * TE_) + s0 + row) * H_ + h0 + col;
    const fx4 v = *(const fx4*)&e[go];
    u16x4 hv, lv;
#pragma unroll
    for (int j = 0; j < 4; ++j) {
      const unsigned short hb = f2bf(v[j]);
      hv[j] = hb;
      lv[j] = f2bf(v[j] - bf2f(hb));   // exact residual (Sterbenz)
      lt[row][col + j] = hb;
    }
    *(u16x4*)&ehi[go] = hv;
    *(u16x4*)&elo[go] = lv;
  }
  __syncthreads();
#pragma unroll
  for (int i = 0; i < 2; ++i) {
    const int idx = tid + 256 * i;     // 0..511
    const int hh = idx >> 3;           // 0..63 (h-local)
    const int sc = (idx & 7) * 8;      // 0..56 (s-local)
    s16x8 v;
#pragma unroll
    for (int j = 0; j < 8; ++j) v[j] = (short)lt[sc + j][hh];
    *(s16x8*)&eT[(((size_t)b * H_) + h0 + hh) * TE_ + s0 + sc] = v;
  }
}

// ---------------- flash: per block 32 q-rows (2 waves x 16), loop KV in steps of 32
__global__ __launch_bounds__(128) void flash(const float* __restrict__ dmat,
                                             const unsigned short* __restrict__ ehi_g,
                                             const unsigned short* __restrict__ elo_g,
                                             const unsigned short* __restrict__ eT_g,
                                             float* __restrict__ value) {
  const int bid = blockIdx.x;     // 256 = 8 batches * 32 q-blocks
  const int b = bid >> 5;
  const int q0 = (bid & 31) * 32;
  const int tid = threadIdx.x;
  const int wave = tid >> 6;
  const int lane = tid & 63;
  const int g = lane >> 4;        // k-group / row-group
  const int c = lane & 15;
  const int qbase = q0 + wave * 16;

  __shared__ unsigned short ehi[32][264];   // pad 256->264: 2-way banks on B-frag reads
  __shared__ unsigned short elo[32][264];
  __shared__ unsigned short eTl[256][40];   // pad 32->40
  __shared__ unsigned short plds[2][16][40];

  // Preload d A-fragments (hi/lo) for this wave's 16 q rows: A[m=c][k=g*8+j]
  s16x8 a_hi[8], a_lo[8];
  {
    const float* drow = dmat + ((size_t)b * TD_ + qbase + c) * H_;
#pragma unroll
    for (int k = 0; k < 8; ++k) {
#pragma unroll
      for (int j = 0; j < 8; ++j) {
        const float x = drow[k * 32 + g * 8 + j];
        const unsigned short hb = f2bf(x);
        a_hi[k][j] = (short)hb;
        a_lo[k][j] = (short)f2bf(x - bf2f(hb));
      }
    }
  }

  fx4 acc[16];
#pragma unroll
  for (int nt = 0; nt < 16; ++nt) acc[nt] = (fx4){0.f, 0.f, 0.f, 0.f};
  float m[4], l[4];
#pragma unroll
  for (int r = 0; r < 4; ++r) { m[r] = -__builtin_inff(); l[r] = 0.f; }

  for (int s0 = 0; s0 < TE_; s0 += 32) {
    // ---- stage e tiles (both waves cooperate)
    const size_t ebase = ((size_t)b * TE_ + s0) * H_;
#pragma unroll
    for (int i = 0; i < 8; ++i) {
      const int chunk = tid + 128 * i;       // 0..1023
      const int s = chunk >> 5;
      const int hc = (chunk & 31) * 8;
      *(s16x8*)&ehi[s][hc] = *(const s16x8*)&ehi_g[ebase + s * H_ + hc];
      *(s16x8*)&elo[s][hc] = *(const s16x8*)&elo_g[ebase + s * H_ + hc];
    }
    const size_t tbase = ((size_t)b * H_) * TE_ + s0;
#pragma unroll
    for (int i = 0; i < 8; ++i) {
      const int chunk = tid + 128 * i;       // 0..1023
      const int h = chunk >> 2;              // 0..255
      const int sc = (chunk & 3) * 8;
      *(s16x8*)&eTl[h][sc] = *(const s16x8*)&eT_g[tbase + (size_t)h * TE_ + sc];
    }
    __syncthreads();

    // ---- QK^T: S[q=g*4+r][s=c+16*t], hi/lo split (hh + lh + hl)
    fx4 sa0 = (fx4){0.f, 0.f, 0.f, 0.f};
    fx4 sa1 = (fx4){0.f, 0.f, 0.f, 0.f};
#pragma unroll
    for (int k = 0; k < 8; ++k) {
      const s16x8 bh0 = *(const s16x8*)&ehi[c][k * 32 + g * 8];
      const s16x8 bl0 = *(const s16x8*)&elo[c][k * 32 + g * 8];
      sa0 = MFMA(a_hi[k], bh0, sa0);
      sa0 = MFMA(a_lo[k], bh0, sa0);
      sa0 = MFMA(a_hi[k], bl0, sa0);
      const s16x8 bh1 = *(const s16x8*)&ehi[16 + c][k * 32 + g * 8];
      const s16x8 bl1 = *(const s16x8*)&elo[16 + c][k * 32 + g * 8];
      sa1 = MFMA(a_hi[k], bh1, sa1);
      sa1 = MFMA(a_lo[k], bh1, sa1);
      sa1 = MFMA(a_hi[k], bl1, sa1);
    }

    // ---- online softmax (rows live on 16 lanes sharing g; reduce over c)
    float al[4], pr0[4], pr1[4];
    {
      float rmax[4], rsum[4];
#pragma unroll
      for (int r = 0; r < 4; ++r) rmax[r] = fmaxf(sa0[r], sa1[r]);
#pragma unroll
      for (int mask = 1; mask <= 8; mask <<= 1)
#pragma unroll
        for (int r = 0; r < 4; ++r) rmax[r] = fmaxf(rmax[r], __shfl_xor(rmax[r], mask, 64));
#pragma unroll
      for (int r = 0; r < 4; ++r) {
        const float mn = fmaxf(m[r], rmax[r]);
        al[r] = __expf(m[r] - mn);           // first iter: exp(-inf)=0
        pr0[r] = __expf(sa0[r] - mn);
        pr1[r] = __expf(sa1[r] - mn);
        m[r] = mn;
        rsum[r] = pr0[r] + pr1[r];
      }
#pragma unroll
      for (int mask = 1; mask <= 8; mask <<= 1)
#pragma unroll
        for (int r = 0; r < 4; ++r) rsum[r] += __shfl_xor(rsum[r], mask, 64);
#pragma unroll
      for (int r = 0; r < 4; ++r) l[r] = l[r] * al[r] + rsum[r];
    }
#pragma unroll
    for (int nt = 0; nt < 16; ++nt) {
#pragma unroll
      for (int r = 0; r < 4; ++r) acc[nt][r] *= al[r];
    }

    // ---- P -> LDS (bf16) to reach A-frag layout, then PV
#pragma unroll
    for (int r = 0; r < 4; ++r) {
      plds[wave][g * 4 + r][c] = f2bf(pr0[r]);
      plds[wave][g * 4 + r][16 + c] = f2bf(pr1[r]);
    }
    const s16x8 pa = *(const s16x8*)&plds[wave][c][g * 8];  // A[m=c][k=g*8+j]
#pragma unroll
    for (int nt = 0; nt < 16; ++nt) {
      const s16x8 bv = *(const s16x8*)&eTl[nt * 16 + c][g * 8];  // B[k][n=nt*16+c]
      acc[nt] = MFMA(pa, bv, acc[nt]);
    }
    __syncthreads();
  }

  // ---- write value = acc / l
#pragma unroll
  for (int nt = 0; nt < 16; ++nt) {
#pragma unroll
    for (int r = 0; r < 4; ++r) {
      value[((size_t)b * TD_ + qbase + g * 4 + r) * H_ + nt * 16 + c] = acc[nt][r] / l[r];
    }
  }
}

// ---------------- dense: out = tanh([value,d] @ W + b), f32 vector GEMM
__global__ __launch_bounds__(256) void dense(const float* __restrict__ value,
                                             const float* __restrict__ dmat,
                                             const float* __restrict__ W,
                                             const float* __restrict__ bias,
                                             float* __restrict__ out) {
  const int row0 = blockIdx.x * 32;   // 256 blocks * 32 rows = 8192
  const int tid = threadIdx.x;
  const int cg = (tid & 63) * 4;      // 4 output cols
  const int rq = (tid >> 6) * 8;      // 8 rows
  __shared__ float xt[32][68];
  float acc[8][4];
#pragma unroll
  for (int r = 0; r < 8; ++r)
#pragma unroll
    for (int j = 0; j < 4; ++j) acc[r][j] = 0.f;

  for (int k0 = 0; k0 < 512; k0 += 64) {
    __syncthreads();
#pragma unroll
    for (int i = 0; i < 2; ++i) {
      const int idx = tid + 256 * i;   // 0..511 -> 32 rows x 16 float4
      const int r = idx >> 4;
      const int c4 = (idx & 15) * 4;
      const int kk = k0 + c4;
      const float* src = (kk < 256)
                             ? &value[((size_t)(row0 + r)) * 256 + kk]
                             : &dmat[((size_t)(row0 + r)) * 256 + (kk - 256)];
      *(fx4*)&xt[r][c4] = *(const fx4*)src;
    }
    __syncthreads();
#pragma unroll
    for (int kk = 0; kk < 64; ++kk) {
      const fx4 w4 = *(const fx4*)&W[((size_t)(k0 + kk)) * 256 + cg];
#pragma unroll
      for (int r = 0; r < 8; ++r) {
        const float xv = xt[rq + r][kk];
#pragma unroll
        for (int j = 0; j < 4; ++j) acc[r][j] += xv * w4[j];
      }
    }
  }
#pragma unroll
  for (int r = 0; r < 8; ++r) {
    fx4 o;
#pragma unroll
    for (int j = 0; j < 4; ++j) o[j] = tanhf(acc[r][j] + bias[cg + j]);
    *(fx4*)&out[((size_t)(row0 + rq + r)) * 256 + cg] = o;
  }
}

extern "C" void kernel_launch(void* const* d_in, const int* in_sizes, int n_in,
                              void* d_out, int out_size, void* d_ws, size_t ws_size,
                              hipStream_t stream) {
  const float* e = (const float*)d_in[0];    // [8,4096,256]
  const float* d = (const float*)d_in[1];    // [8,1024,256]
  const float* W = (const float*)d_in[2];    // [512,256]
  const float* bias = (const float*)d_in[3]; // [256]
  float* out = (float*)d_out;                // [8,1024,256]

  char* w = (char*)d_ws;
  const size_t EB = (size_t)B_ * TE_ * H_ * 2;  // 16 MiB per bf16 e-copy
  unsigned short* ehi = (unsigned short*)w;
  unsigned short* elo = (unsigned short*)(w + EB);
  unsigned short* eT = (unsigned short*)(w + 2 * EB);
  float* value = (float*)(w + 3 * EB);          // 8 MiB; total ws use = 56 MiB

  prep_e<<<dim3(2048), dim3(256), 0, stream>>>(e, ehi, elo, eT);
  flash<<<dim3(256), dim3(128), 0, stream>>>(d, ehi, elo, eT, value);
  dense<<<dim3(256), dim3(256), 0, stream>>>(value, d, W, bias, out);
}

// Round 2
// 189.858 us; speedup vs baseline: 5.4514x; 5.4514x over previous
//
#include <hip/hip_runtime.h>

// Attention_Layer: scores=d@e^T -> softmax -> value=attn@e -> tanh([value,d]@W+b)
// B=8 TE=4096 TD=1024 H=256 NH=256, f32 in/out.
// Round 2: KV-split flash (NS=4), swapped-operand MFMA (A=e, B=d-in-regs),
// XOR-swizzled LDS, global_load_lds for eT tile, in-loop trunc hi/lo split of e.

#define B_ 8
#define TE_ 4096
#define TD_ 1024
#define H_ 256
#define NS_ 4
#define CHUNK_ (TE_ / NS_)
#define NROW_ (B_ * TD_)

typedef __attribute__((ext_vector_type(8))) short s16x8;
typedef __attribute__((ext_vector_type(4))) float fx4;
typedef __attribute__((ext_vector_type(4))) unsigned short u16x4;

#define MFMA(a, b, c) __builtin_amdgcn_mfma_f32_16x16x32_bf16(a, b, c, 0, 0, 0)

__device__ __forceinline__ unsigned short f2bf(float x) {
  unsigned u = __float_as_uint(x);
  unsigned r = (u + 0x7fffu + ((u >> 16) & 1u)) >> 16;  // RNE
  return (unsigned short)r;
}
__device__ __forceinline__ float bf2f(unsigned short s) {
  return __uint_as_float(((unsigned)s) << 16);
}
// pack bf16(trunc) pair: lo half = bf16(f0), hi half = bf16(f1)
__device__ __forceinline__ unsigned hipack(unsigned f0, unsigned f1) {
  return (f0 >> 16) | (f1 & 0xFFFF0000u);
}
__device__ __forceinline__ unsigned lopack(unsigned f0, unsigned f1) {
  const float r0 = __uint_as_float(f0) - __uint_as_float(f0 & 0xFFFF0000u);
  const float r1 = __uint_as_float(f1) - __uint_as_float(f1 & 0xFFFF0000u);
  return (__float_as_uint(r0) >> 16) | (__float_as_uint(r1) & 0xFFFF0000u);
}
__device__ __forceinline__ void gload_lds16(const void* g, void* l) {
  __builtin_amdgcn_global_load_lds(
      (const __attribute__((address_space(1))) void*)g,
      (__attribute__((address_space(3))) void*)l, 16, 0, 0);
}

// ---------------- prep_eT: e(f32) -> eT bf16 [B,H,TE] (RNE hi)
__global__ __launch_bounds__(256) void prep_eT(const float* __restrict__ e,
                                               unsigned short* __restrict__ eT) {
  const int bid = blockIdx.x;          // 8 * 64 * 4 = 2048 blocks
  const int b = bid >> 8;
  const int s0 = ((bid >> 2) & 63) * 64;
  const int h0 = (bid & 3) * 64;
  const int tid = threadIdx.x;
  __shared__ unsigned short lt[64][65];

#pragma unroll
  for (int i = 0; i < 4; ++i) {
    const int row = (tid >> 4) + 16 * i;
    const int col = (tid & 15) * 4;
    const size_t go = (((size_t)b * TE_) + s0 + row) * H_ + h0 + col;
    const fx4 v = *(const fx4*)&e[go];
#pragma unroll
    for (int j = 0; j < 4; ++j) lt[row][col + j] = f2bf(v[j]);
  }
  __syncthreads();
#pragma unroll
  for (int i = 0; i < 2; ++i) {
    const int idx = tid + 256 * i;     // 0..511
    const int hh = idx >> 3;           // h-local
    const int sc = (idx & 7) * 8;      // s-local
    s16x8 v;
#pragma unroll
    for (int j = 0; j < 8; ++j) v[j] = (short)lt[sc + j][hh];
    *(s16x8*)&eT[(((size_t)b * H_) + h0 + hh) * TE_ + s0 + sc] = v;
  }
}

// ---------------- flash2: 512 blocks = 8 b x 16 q-blk(64) x 4 ns; 4 waves x 16 q
__global__ __launch_bounds__(256, 2) void flash2(
    const float* __restrict__ e, const float* __restrict__ dmat,
    const unsigned short* __restrict__ eT,
    float* __restrict__ pacc, float* __restrict__ pm, float* __restrict__ pl) {
  const int bid = blockIdx.x;
  const int b = bid >> 6;
  const int q0 = ((bid >> 2) & 15) * 64;
  const int ns = bid & 3;
  const int cs = ns * CHUNK_;
  const int tid = threadIdx.x;
  const int wq = tid >> 6;
  const int lane = tid & 63;
  const int g = lane >> 4, c = lane & 15;
  const int qrow = q0 + wq * 16 + c;

  __shared__ uint4 ehi_l[32 * 32];   // 16 KB, row=s(32) x 32 chunks, XOR(s&7)
  __shared__ uint4 elo_l[32 * 32];   // 16 KB
  __shared__ uint4 etl_l[256 * 4];   // 16 KB, row=h(256) x 4 chunks, XOR((h>>1)&3)

  // ---- d B-frags hi/lo (registers, once): b[j] = d[qrow][kk*32+g*8+j]
  s16x8 bd_h[8], bd_l[8];
  {
    const float* dr = dmat + ((size_t)b * TD_ + qrow) * H_;
#pragma unroll
    for (int kk = 0; kk < 8; ++kk) {
      const fx4 x0 = *(const fx4*)&dr[kk * 32 + g * 8];
      const fx4 x1 = *(const fx4*)&dr[kk * 32 + g * 8 + 4];
      s16x8 hh, ll;
#pragma unroll
      for (int j = 0; j < 4; ++j) {
        unsigned short hb = f2bf(x0[j]);
        hh[j] = (short)hb; ll[j] = (short)f2bf(x0[j] - bf2f(hb));
        hb = f2bf(x1[j]);
        hh[4 + j] = (short)hb; ll[4 + j] = (short)f2bf(x1[j] - bf2f(hb));
      }
      bd_h[kk] = hh; bd_l[kk] = ll;
    }
  }

  fx4 acc[16];
#pragma unroll
  for (int nt = 0; nt < 16; ++nt) acc[nt] = (fx4){0.f, 0.f, 0.f, 0.f};
  float m = -__builtin_inff(), l = 0.f;

  const int xr = c & 7;                 // A-frag slot XOR (rows c and 16+c)
  const int slv = g ^ ((c >> 1) & 3);   // etl slot XOR (nt-independent)

  for (int it = 0; it < CHUNK_ / 32; ++it) {
    const int s0 = cs + it * 32;
    // ---- stage eT tile (global_load_lds, 16B, pre-swizzled source)
    const unsigned short* tbase = eT + (size_t)b * H_ * TE_ + s0;
#pragma unroll
    for (int i = 0; i < 4; ++i) {
      const int L = tid + 256 * i;     // 0..1023
      const int h = L >> 2, c4 = L & 3;
      const int sch = c4 ^ ((h >> 1) & 3);
      gload_lds16(tbase + (size_t)h * TE_ + sch * 8, &etl_l[L]);
    }
    // ---- stage e tile: f32 -> trunc hi/lo bf16, swizzled ds_write
    const float* ebase = e + ((size_t)b * TE_ + s0) * H_;
#pragma unroll
    for (int i = 0; i < 4; ++i) {
      const int P = tid + 256 * i;     // 0..1023 (32B groups)
      const int s = P >> 5, cp = P & 31;
      const uint4* src = (const uint4*)(ebase + (size_t)s * H_ + cp * 8);
      const uint4 w0 = src[0], w1 = src[1];
      uint4 hv, lv;
      hv.x = hipack(w0.x, w0.y); hv.y = hipack(w0.z, w0.w);
      hv.z = hipack(w1.x, w1.y); hv.w = hipack(w1.z, w1.w);
      lv.x = lopack(w0.x, w0.y); lv.y = lopack(w0.z, w0.w);
      lv.z = lopack(w1.x, w1.y); lv.w = lopack(w1.z, w1.w);
      const int slot = s * 32 + (cp ^ (s & 7));
      ehi_l[slot] = hv; elo_l[slot] = lv;
    }
    __syncthreads();

    // ---- QK^T (swapped): S^T[s][q], A=e hi/lo from LDS, B=d from regs
    fx4 sa0 = (fx4){0.f, 0.f, 0.f, 0.f};
    fx4 sa1 = (fx4){0.f, 0.f, 0.f, 0.f};
#pragma unroll
    for (int kk = 0; kk < 8; ++kk) {
      const int sl = (kk * 4 + g) ^ xr;
      const s16x8 ah0 = *(const s16x8*)&ehi_l[c * 32 + sl];
      const s16x8 al0 = *(const s16x8*)&elo_l[c * 32 + sl];
      const s16x8 ah1 = *(const s16x8*)&ehi_l[(16 + c) * 32 + sl];
      const s16x8 al1 = *(const s16x8*)&elo_l[(16 + c) * 32 + sl];
      sa0 = MFMA(ah0, bd_h[kk], sa0);
      sa0 = MFMA(al0, bd_h[kk], sa0);
      sa0 = MFMA(ah0, bd_l[kk], sa0);
      sa1 = MFMA(ah1, bd_h[kk], sa1);
      sa1 = MFMA(al1, bd_h[kk], sa1);
      sa1 = MFMA(ah1, bd_l[kk], sa1);
    }

    // ---- online softmax (column q=c spans lanes g=0..3: 2 shfl rounds)
    float mx = fmaxf(fmaxf(fmaxf(sa0[0], sa0[1]), fmaxf(sa0[2], sa0[3])),
                     fmaxf(fmaxf(sa1[0], sa1[1]), fmaxf(sa1[2], sa1[3])));
    mx = fmaxf(mx, __shfl_xor(mx, 16, 64));
    mx = fmaxf(mx, __shfl_xor(mx, 32, 64));
    if (!__all(mx <= m + 4.0f)) {      // defer-max (exact math)
      const float nm = fmaxf(m, mx);
      const float al = __expf(m - nm);
      m = nm; l *= al;
#pragma unroll
      for (int nt = 0; nt < 16; ++nt) {
#pragma unroll
        for (int r = 0; r < 4; ++r) acc[nt][r] *= al;
      }
    }
    float t0[4], t1[4];                // trunc-bf16-rounded p values (as f32)
    float rs = 0.f;
#pragma unroll
    for (int r = 0; r < 4; ++r) {
      const float p0 = __expf(sa0[r] - m);
      const float p1 = __expf(sa1[r] - m);
      t0[r] = __uint_as_float(__float_as_uint(p0) & 0xFFFF0000u);
      t1[r] = __uint_as_float(__float_as_uint(p1) & 0xFFFF0000u);
      rs += t0[r] + t1[r];             // l matches bf16 P exactly
    }
    rs += __shfl_xor(rs, 16, 64);
    rs += __shfl_xor(rs, 32, 64);
    l += rs;

    // ---- pack P^T to bf16 pairs, gather PV B-frags via shfl
    const unsigned pk00 = hipack(__float_as_uint(t0[0]), __float_as_uint(t0[1]));
    const unsigned pk01 = hipack(__float_as_uint(t0[2]), __float_as_uint(t0[3]));
    const unsigned pk10 = hipack(__float_as_uint(t1[0]), __float_as_uint(t1[1]));
    const unsigned pk11 = hipack(__float_as_uint(t1[2]), __float_as_uint(t1[3]));
    const int src0 = ((g & 1) << 5) + c;
    const int src1 = src0 + 16;
    const unsigned a0 = __shfl(pk00, src0, 64);
    const unsigned a1 = __shfl(pk01, src0, 64);
    const unsigned a2 = __shfl(pk00, src1, 64);
    const unsigned a3 = __shfl(pk01, src1, 64);
    const unsigned b0 = __shfl(pk10, src0, 64);
    const unsigned b1 = __shfl(pk11, src0, 64);
    const unsigned b2 = __shfl(pk10, src1, 64);
    const unsigned b3 = __shfl(pk11, src1, 64);
    const bool hiT = (g >= 2);
    union { unsigned u[4]; s16x8 v; } pb;
    pb.u[0] = hiT ? b0 : a0; pb.u[1] = hiT ? b1 : a1;
    pb.u[2] = hiT ? b2 : a2; pb.u[3] = hiT ? b3 : a3;

    // ---- PV: value^T[h][q] += eT-tile * P^T
#pragma unroll
    for (int nt = 0; nt < 16; ++nt) {
      const s16x8 ea = *(const s16x8*)&etl_l[(nt * 16 + c) * 4 + slv];
      acc[nt] = MFMA(ea, pb.v, acc[nt]);
    }
    __syncthreads();
  }

  // ---- write partials: pacc[ns][R][h], pm/pl[ns][R]
  const size_t R = (size_t)b * TD_ + q0 + wq * 16 + c;
  float* prow = pacc + ((size_t)ns * NROW_ + R) * H_;
#pragma unroll
  for (int nt = 0; nt < 16; ++nt) {
    *(fx4*)&prow[nt * 16 + g * 4] = acc[nt];
  }
  if (g == 0) {
    pm[ns * NROW_ + R] = m;
    pl[ns * NROW_ + R] = l;
  }
}

// ---------------- combine: value[R][h] = sum_s w_s pacc_s / sum_s w_s l_s
__global__ __launch_bounds__(256) void combine(const float* pacc, const float* pm,
                                               const float* pl, float* value) {
  const int t = blockIdx.x * 256 + threadIdx.x;   // 262144 threads
  const int R = t >> 5;
  const int col = (t & 31) * 8;
  float pms[NS_], pls[NS_];
#pragma unroll
  for (int s = 0; s < NS_; ++s) {
    pms[s] = pm[s * NROW_ + R];
    pls[s] = pl[s * NROW_ + R];
  }
  float M = pms[0];
#pragma unroll
  for (int s = 1; s < NS_; ++s) M = fmaxf(M, pms[s]);
  float L = 0.f, w[NS_];
#pragma unroll
  for (int s = 0; s < NS_; ++s) { w[s] = __expf(pms[s] - M); L += w[s] * pls[s]; }
  const float inv = 1.0f / L;
  float o[8];
#pragma unroll
  for (int j = 0; j < 8; ++j) o[j] = 0.f;
#pragma unroll
  for (int s = 0; s < NS_; ++s) {
    const fx4 v0 = *(const fx4*)&pacc[((size_t)s * NROW_ + R) * H_ + col];
    const fx4 v1 = *(const fx4*)&pacc[((size_t)s * NROW_ + R) * H_ + col + 4];
#pragma unroll
    for (int j = 0; j < 4; ++j) { o[j] += w[s] * v0[j]; o[4 + j] += w[s] * v1[j]; }
  }
  fx4 y0, y1;
#pragma unroll
  for (int j = 0; j < 4; ++j) { y0[j] = o[j] * inv; y1[j] = o[4 + j] * inv; }
  *(fx4*)&value[(size_t)R * H_ + col] = y0;        // value aliases pacc[0]
  *(fx4*)&value[(size_t)R * H_ + col + 4] = y1;    // loads above precede stores
}

// ---------------- dense: out = tanh([value,d] @ W + b), f32 vector GEMM
__global__ __launch_bounds__(256) void dense(const float* __restrict__ value,
                                             const float* __restrict__ dmat,
                                             const float* __restrict__ W,
                                             const float* __restrict__ bias,
                                             float* __restrict__ out) {
  const int row0 = blockIdx.x * 32;
  const int tid = threadIdx.x;
  const int cg = (tid & 63) * 4;
  const int rq = (tid >> 6) * 8;
  __shared__ float xt[32][68];
  float acc[8][4];
#pragma unroll
  for (int r = 0; r < 8; ++r)
#pragma unroll
    for (int j = 0; j < 4; ++j) acc[r][j] = 0.f;

  for (int k0 = 0; k0 < 512; k0 += 64) {
    __syncthreads();
#pragma unroll
    for (int i = 0; i < 2; ++i) {
      const int idx = tid + 256 * i;
      const int r = idx >> 4;
      const int c4 = (idx & 15) * 4;
      const int kk = k0 + c4;
      const float* src = (kk < 256)
                             ? &value[((size_t)(row0 + r)) * 256 + kk]
                             : &dmat[((size_t)(row0 + r)) * 256 + (kk - 256)];
      *(fx4*)&xt[r][c4] = *(const fx4*)src;
    }
    __syncthreads();
#pragma unroll
    for (int kk = 0; kk < 64; ++kk) {
      const fx4 w4 = *(const fx4*)&W[((size_t)(k0 + kk)) * 256 + cg];
#pragma unroll
      for (int r = 0; r < 8; ++r) {
        const float xv = xt[rq + r][kk];
#pragma unroll
        for (int j = 0; j < 4; ++j) acc[r][j] += xv * w4[j];
      }
    }
  }
#pragma unroll
  for (int r = 0; r < 8; ++r) {
    fx4 o;
#pragma unroll
    for (int j = 0; j < 4; ++j) o[j] = tanhf(acc[r][j] + bias[cg + j]);
    *(fx4*)&out[((size_t)(row0 + rq + r)) * 256 + cg] = o;
  }
}

extern "C" void kernel_launch(void* const* d_in, const int* in_sizes, int n_in,
                              void* d_out, int out_size, void* d_ws, size_t ws_size,
                              hipStream_t stream) {
  const float* e = (const float*)d_in[0];    // [8,4096,256]
  const float* d = (const float*)d_in[1];    // [8,1024,256]
  const float* W = (const float*)d_in[2];    // [512,256]
  const float* bias = (const float*)d_in[3]; // [256]
  float* out = (float*)d_out;

  char* w = (char*)d_ws;
  const size_t ETB = (size_t)B_ * H_ * TE_ * 2;            // 16 MiB (eT bf16)
  const size_t PACCB = (size_t)NS_ * NROW_ * H_ * 4;       // 32 MiB (pacc f32)
  unsigned short* eT = (unsigned short*)w;
  float* pacc = (float*)(w + ETB);
  float* pmv = (float*)(w + ETB + PACCB);
  float* plv = pmv + NS_ * NROW_;
  float* value = pacc;                                     // overlays pacc[0]

  prep_eT<<<dim3(2048), dim3(256), 0, stream>>>(e, eT);
  flash2<<<dim3(512), dim3(256), 0, stream>>>(e, d, eT, pacc, pmv, plv);
  combine<<<dim3(1024), dim3(256), 0, stream>>>(pacc, pmv, plv, value);
  dense<<<dim3(256), dim3(256), 0, stream>>>(value, d, W, bias, out);
}